// Round 5
// baseline (87.237 us; speedup 1.0000x reference)
//
#include <hip/hip_runtime.h>

typedef __attribute__((ext_vector_type(8))) short short8;
typedef __attribute__((ext_vector_type(4))) short bf16x4;
typedef __attribute__((ext_vector_type(4))) float f32x4;
typedef unsigned short ushort_t;

#define MFMA(a, b, c) __builtin_amdgcn_mfma_f32_16x16x32_bf16((a), (b), (c), 0, 0, 0)

constexpr int NB = 32, NHt = 128, NWd = 128, NC = 64, MX = 32;
constexpr float TWO_PI = 6.28318530717958647692f;

// workspace layout (64 KB tables + 8 MiB X/Y buffer)
constexpr size_t TAB_T1 = 0;      // K1 stage1 A: F128 fwd  [mt2][ks4][lane64][re8,im8]
constexpr size_t TAB_T2 = 16384;  // K1 stage2 B: G64  fwd  [nt4][ks2][lane64][re8,im8]
constexpr size_t TAB_T3 = 32768;  // K3 stage4 B: G64  inv  [nt4][ks2][lane64][re8,im8]
constexpr size_t TAB_T4 = 49152;  // K3 stage5 A: G128 inv  [mt8][lane64][re8,im8] (x 1/8192)
constexpr size_t XY_OFF = 65536;  // X then Y in-place: bf16 [h32][u32][comp2][b32][k64]

__device__ inline ushort_t f2bf(float f) {
    union { float f; unsigned int u; } v; v.f = f;
    unsigned int r = v.u + 0x7FFFu + ((v.u >> 16) & 1u);   // RTN-even
    return (ushort_t)(r >> 16);
}
// row-dependent XOR swizzle (bits 4-5): breaks the {0,16} bank pattern of
// power-of-two-ish row strides; 16B-granular so ds_read_b128 stays aligned.
__device__ inline int sxor(int row) { return ((row >> 3) & 3) << 4; }

// ---------------------------------------------------------------------------
// K0: twiddle fragment tables in exact MFMA A/B lane layout.
// ---------------------------------------------------------------------------
__global__ __launch_bounds__(256) void k0_tables(ushort_t* __restrict__ tabs)
{
    int e = blockIdx.x * 256 + threadIdx.x;   // 0..2047
    int tab = e >> 9, rem = e & 511;
    float re[8], im[8];
    if (tab == 0) {            // F128 fwd: exp(-2pi i u w/128)
        int mt = rem >> 8, ks = (rem >> 6) & 3, l = rem & 63;
        int uu = (l & 15) + 16 * mt, wb = (l >> 4) * 8 + 32 * ks;
        #pragma unroll
        for (int j = 0; j < 8; ++j) {
            float a = (float)((uu * (wb + j)) & 127) * (TWO_PI / 128.f);
            re[j] = cosf(a); im[j] = -sinf(a);
        }
    } else if (tab == 1) {     // G64 fwd: exp(-2pi i k c/64), col=k, k'=c
        int nt = rem >> 7, ks = (rem >> 6) & 1, l = rem & 63;
        int kk = (l & 15) + 16 * nt, cb2 = (l >> 4) * 8 + 32 * ks;
        #pragma unroll
        for (int j = 0; j < 8; ++j) {
            float a = (float)((kk * (cb2 + j)) & 63) * (TWO_PI / 64.f);
            re[j] = cosf(a); im[j] = -sinf(a);
        }
    } else if (tab == 2) {     // G64 inv: exp(+2pi i o c/64), col=c, k'=o
        int nt = rem >> 7, ks = (rem >> 6) & 1, l = rem & 63;
        int cc = (l & 15) + 16 * nt, ob = (l >> 4) * 8 + 32 * ks;
        #pragma unroll
        for (int j = 0; j < 8; ++j) {
            float a = (float)(((ob + j) * cc) & 63) * (TWO_PI / 64.f);
            re[j] = cosf(a); im[j] = sinf(a);
        }
    } else {                   // G128 inv: exp(+2pi i w u/128) / 8192, row=w, k=u
        int mt = rem >> 6, l = rem & 63;
        int w = (l & 15) + 16 * mt, ub = (l >> 4) * 8;
        #pragma unroll
        for (int j = 0; j < 8; ++j) {
            float a = (float)((w * (ub + j)) & 127) * (TWO_PI / 128.f);
            re[j] = cosf(a) * 0.0001220703125f;  // exact 2^-13, lossless in bf16
            im[j] = sinf(a) * 0.0001220703125f;
        }
    }
    ushort_t* dst = tabs + (size_t)e * 16;
    #pragma unroll
    for (int j = 0; j < 8; ++j) { dst[j] = f2bf(re[j]); dst[8 + j] = f2bf(im[j]); }
}

// ---------------------------------------------------------------------------
// K1: per (b, h<32). M1 = F128trunc . x  (32x64 cplx), X = M1 . G64fwd.
// ---------------------------------------------------------------------------
__global__ __launch_bounds__(512) void k1_fwd(
    const float* __restrict__ x, const char* __restrict__ tabs, ushort_t* __restrict__ XY)
{
    const int b = blockIdx.x, h = blockIdx.y;
    const int tid = threadIdx.x, lane = tid & 63, wv = tid >> 6;
    constexpr int SXT  = 0;            // x^T bf16 [c64][w128], stride 272B; reused for X-out
    constexpr int M1RE = 17408;        // [u32][c64+pad], stride 144B
    constexpr int M1IM = 17408 + 4608;
    __shared__ __align__(16) char sm[26624];

    // load x slice (float4) + transpose -> sxT[c][w] bf16 (swizzled)
    const float* xs = x + ((size_t)(b * NHt + h)) * (NWd * NC);
    #pragma unroll
    for (int i = 0; i < 4; ++i) {
        int idx = tid + 512 * i;               // 0..2047 float4s
        int w = idx >> 4, c4 = (idx & 15) * 4;
        f32x4 v = *reinterpret_cast<const f32x4*>(xs + w * 64 + c4);
        #pragma unroll
        for (int j = 0; j < 4; ++j)
            *(ushort_t*)(sm + SXT + (c4 + j) * 272 + ((w * 2) ^ sxor(c4 + j))) = f2bf(v[j]);
    }
    __syncthreads();

    const int mt = wv >> 2, nt = wv & 3;
    // stage 1: M1[u,c] = sum_w F[u,w] x[w,c]
    f32x4 m1r = {0.f,0.f,0.f,0.f}, m1i = {0.f,0.f,0.f,0.f};
    const int cc = (lane & 15) + 16 * nt;
    #pragma unroll
    for (int ks = 0; ks < 4; ++ks) {
        short8 bfrag = *reinterpret_cast<const short8*>(
            sm + SXT + cc * 272 + (((lane >> 4) * 16 + 64 * ks) ^ sxor(cc)));
        const char* t1 = tabs + TAB_T1 + (((mt * 4 + ks) * 64 + lane) * 32);
        short8 are = *reinterpret_cast<const short8*>(t1);
        short8 aim = *reinterpret_cast<const short8*>(t1 + 16);
        m1r = MFMA(are, bfrag, m1r);
        m1i = MFMA(aim, bfrag, m1i);
    }
    #pragma unroll
    for (int r = 0; r < 4; ++r) {
        int u = (lane >> 4) * 4 + r + 16 * mt;
        int c = (lane & 15) + 16 * nt;
        *(ushort_t*)(sm + M1RE + u * 144 + c * 2) = f2bf(m1r[r]);
        *(ushort_t*)(sm + M1IM + u * 144 + c * 2) = f2bf(m1i[r]);
    }
    __syncthreads();

    // stage 2: X[u,k] = sum_c M1[u,c] G64f[c,k]; fragments -> LDS [comp][u][k]
    f32x4 xP = {0.f,0.f,0.f,0.f}, xQ = {0.f,0.f,0.f,0.f}, xI = {0.f,0.f,0.f,0.f};
    #pragma unroll
    for (int ks = 0; ks < 2; ++ks) {
        short8 are = *reinterpret_cast<const short8*>(
            sm + M1RE + ((lane & 15) + 16 * mt) * 144 + (lane >> 4) * 16 + 64 * ks);
        short8 aim = *reinterpret_cast<const short8*>(
            sm + M1IM + ((lane & 15) + 16 * mt) * 144 + (lane >> 4) * 16 + 64 * ks);
        const char* t2 = tabs + TAB_T2 + (((nt * 2 + ks) * 64 + lane) * 32);
        short8 bre = *reinterpret_cast<const short8*>(t2);
        short8 bim = *reinterpret_cast<const short8*>(t2 + 16);
        xP = MFMA(are, bre, xP);
        xQ = MFMA(aim, bim, xQ);
        xI = MFMA(are, bim, xI);
        xI = MFMA(aim, bre, xI);
    }
    #pragma unroll
    for (int r = 0; r < 4; ++r) {
        int u = (lane >> 4) * 4 + r + 16 * mt;
        int k = (lane & 15) + 16 * nt;
        *(ushort_t*)(sm + SXT + 0    + u * 128 + k * 2) = f2bf(xP[r] - xQ[r]);
        *(ushort_t*)(sm + SXT + 4096 + u * 128 + k * 2) = f2bf(xI[r]);
    }
    __syncthreads();

    // coalesced X store: thread -> (u, comp, k8)
    {
        int u = tid >> 4, comp = (tid >> 3) & 1, k8 = (tid & 7) * 8;
        short8 v = *reinterpret_cast<const short8*>(sm + SXT + comp * 4096 + u * 128 + k8 * 2);
        size_t hu = (size_t)(h * 32 + u);
        *reinterpret_cast<short8*>(XY + ((hu * 2 + comp) * 32 + b) * 64 + k8) = v;
    }
}

// ---------------------------------------------------------------------------
// K2: per (h, u). Y[b,o] = sum_k X[b,k] W[h,u,k,o] — b-batched so W is read
// from HBM exactly once.
// ---------------------------------------------------------------------------
__global__ __launch_bounds__(256) void k2_mix(
    const float* __restrict__ wre, const float* __restrict__ wim, ushort_t* __restrict__ XY)
{
    const int h = blockIdx.x, u = blockIdx.y;
    const int tid = threadIdx.x, lane = tid & 63, wv = tid >> 6;   // 4 waves
    constexpr int XRE = 0, XIM = 4608, WTR = 9216, WTI = 18432;    // strides 144B
    __shared__ __align__(16) char sm[27648];
    const size_t hu = (size_t)(h * 32 + u);

    #pragma unroll
    for (int it = 0; it < 2; ++it) {        // stage X[b][k] (both comps)
        int row = (tid >> 3) + 32 * it;
        int comp = row >> 5, bb = row & 31, k8 = (tid & 7) * 8;
        short8 v = *reinterpret_cast<const short8*>(XY + ((hu * 2 + comp) * 32 + bb) * 64 + k8);
        *reinterpret_cast<short8*>(sm + (comp ? XIM : XRE) + bb * 144 + k8 * 2) = v;
    }
    const float* wr = wre + hu * 4096;      // transpose W -> WT[o][k] bf16 (swizzled)
    const float* wi = wim + hu * 4096;
    #pragma unroll
    for (int i = 0; i < 4; ++i) {
        int idx = tid + 256 * i;            // 0..1023
        int k = idx >> 4, o4 = (idx & 15) * 4;
        f32x4 vr = __builtin_nontemporal_load(reinterpret_cast<const f32x4*>(wr + k * 64 + o4));
        f32x4 vi = __builtin_nontemporal_load(reinterpret_cast<const f32x4*>(wi + k * 64 + o4));
        #pragma unroll
        for (int j = 0; j < 4; ++j) {
            int o = o4 + j, koff = (k * 2) ^ sxor(o);
            *(ushort_t*)(sm + WTR + o * 144 + koff) = f2bf(vr[j]);
            *(ushort_t*)(sm + WTI + o * 144 + koff) = f2bf(vi[j]);
        }
    }
    __syncthreads();

    const int mt = wv >> 1;
    f32x4 yRe[2], yIm[2];
    #pragma unroll
    for (int half = 0; half < 2; ++half) {
        const int nt = (wv & 1) * 2 + half;
        const int oo = (lane & 15) + 16 * nt;
        f32x4 yP = {0.f,0.f,0.f,0.f}, yQ = {0.f,0.f,0.f,0.f}, yI = {0.f,0.f,0.f,0.f};
        #pragma unroll
        for (int ks = 0; ks < 2; ++ks) {
            int woff = ((lane >> 4) * 16 + 64 * ks) ^ sxor(oo);
            short8 are = *reinterpret_cast<const short8*>(
                sm + XRE + ((lane & 15) + 16 * mt) * 144 + (lane >> 4) * 16 + 64 * ks);
            short8 aim = *reinterpret_cast<const short8*>(
                sm + XIM + ((lane & 15) + 16 * mt) * 144 + (lane >> 4) * 16 + 64 * ks);
            short8 bre = *reinterpret_cast<const short8*>(sm + WTR + oo * 144 + woff);
            short8 bim = *reinterpret_cast<const short8*>(sm + WTI + oo * 144 + woff);
            yP = MFMA(are, bre, yP); yQ = MFMA(aim, bim, yQ);
            yI = MFMA(are, bim, yI); yI = MFMA(aim, bre, yI);
        }
        #pragma unroll
        for (int r = 0; r < 4; ++r) { yRe[half][r] = yP[r] - yQ[r]; yIm[half][r] = yI[r]; }
    }
    __syncthreads();   // X region dead; reuse as Y-out [comp][b][o] bf16

    #pragma unroll
    for (int half = 0; half < 2; ++half) {
        const int nt = (wv & 1) * 2 + half;
        #pragma unroll
        for (int r = 0; r < 4; ++r) {
            int bb = (lane >> 4) * 4 + r + 16 * mt;
            int o = (lane & 15) + 16 * nt;
            *(ushort_t*)(sm + 0    + bb * 128 + o * 2) = f2bf(yRe[half][r]);
            *(ushort_t*)(sm + 4096 + bb * 128 + o * 2) = f2bf(yIm[half][r]);
        }
    }
    __syncthreads();

    #pragma unroll
    for (int it = 0; it < 2; ++it) {        // coalesced Y store: 8 KB contiguous
        int flat = tid + 256 * it;          // (comp,b,o8) in global order
        short8 v = *reinterpret_cast<const short8*>(sm + flat * 16);
        *reinterpret_cast<short8*>(XY + hu * 4096 + flat * 8) = v;
    }
}

// ---------------------------------------------------------------------------
// K3a (h<32): S = Y.G64inv, spec = Re(G128inv.S) (1/8192 in table) + conv.
// ---------------------------------------------------------------------------
__global__ __launch_bounds__(512, 4) void k3_spec(
    const float* __restrict__ x, const float* __restrict__ cw, const float* __restrict__ cb,
    const char* __restrict__ tabs, const ushort_t* __restrict__ XY, float* __restrict__ out)
{
    const int b = blockIdx.x, h = blockIdx.y;   // h < 32
    const int tid = threadIdx.x, lane = tid & 63, wv = tid >> 6;
    constexpr int ST_RE = 0, ST_IM = 5120;   // S^T [c64][u32+pad], stride 80B
    constexpr int XB   = 10240;              // x bf16 [w128][c64+pad], stride 144B
    constexpr int CWT  = 28672;              // conv_w^T [o64][i64+pad], stride 144B
    constexpr int SCB  = 37888;              // bias f32[64]
    constexpr int OUTB = 38144;              // out f32 [w128][c64+4pad], stride 272B
    constexpr int YRE  = 38144;              // Y staging inside OUTB (dead by store time)
    constexpr int YIM  = 38144 + 4608;       // strides 144B
    __shared__ __align__(16) char sm[72960];

    // ---- issue all global loads up front ----
    const float* xs = x + ((size_t)(b * NHt + h)) * (NWd * NC);
    f32x4 xv[4];
    #pragma unroll
    for (int i = 0; i < 4; ++i) {
        int idx = tid + 512 * i;
        int w = idx >> 4, c4 = (idx & 15) * 4;
        xv[i] = __builtin_nontemporal_load(reinterpret_cast<const f32x4*>(xs + w * 64 + c4));
    }
    short8 yv, gre, gim;
    {
        int u = tid >> 4, comp = (tid >> 3) & 1, o8 = (tid & 7) * 8;
        size_t hu = (size_t)(h * 32 + u);
        yv = *reinterpret_cast<const short8*>(XY + ((hu * 2 + comp) * 32 + b) * 64 + o8);
        const char* t4 = tabs + TAB_T4 + ((wv * 64 + lane) * 32);
        gre = *reinterpret_cast<const short8*>(t4);
        gim = *reinterpret_cast<const short8*>(t4 + 16);
    }

    // ---- stage x (bf16, packed 8B writes), conv_w^T, bias, Y ----
    #pragma unroll
    for (int i = 0; i < 4; ++i) {
        int idx = tid + 512 * i;
        int w = idx >> 4, c4 = (idx & 15) * 4;
        bf16x4 pk = { (short)f2bf(xv[i][0]), (short)f2bf(xv[i][1]),
                      (short)f2bf(xv[i][2]), (short)f2bf(xv[i][3]) };
        *reinterpret_cast<bf16x4*>(sm + XB + w * 144 + c4 * 2) = pk;
    }
    #pragma unroll
    for (int i = 0; i < 2; ++i) {
        int ii = (tid >> 4) + 32 * i;
        #pragma unroll
        for (int j = 0; j < 4; ++j) {
            int o = (tid & 15) + 16 * j;
            *(ushort_t*)(sm + CWT + o * 144 + ii * 2) = f2bf(cw[ii * 64 + o]);
        }
    }
    if (tid < 64) ((float*)(sm + SCB))[tid] = cb[tid];
    {
        int u = tid >> 4, comp = (tid >> 3) & 1, o8 = (tid & 7) * 8;
        *reinterpret_cast<short8*>(sm + (comp ? YIM : YRE) + u * 144 + o8 * 2) = yv;
    }
    __syncthreads();

    // stage 4: S[u,c] = sum_o Y[u,o] G64inv[o,c]; write S transposed [c][u]
    {
        const int mt = wv >> 2, nt = wv & 3;
        f32x4 sP = {0.f,0.f,0.f,0.f}, sQ = {0.f,0.f,0.f,0.f}, sI = {0.f,0.f,0.f,0.f};
        #pragma unroll
        for (int ks = 0; ks < 2; ++ks) {
            short8 are = *reinterpret_cast<const short8*>(
                sm + YRE + ((lane & 15) + 16 * mt) * 144 + (lane >> 4) * 16 + 64 * ks);
            short8 aim = *reinterpret_cast<const short8*>(
                sm + YIM + ((lane & 15) + 16 * mt) * 144 + (lane >> 4) * 16 + 64 * ks);
            const char* t3 = tabs + TAB_T3 + (((nt * 2 + ks) * 64 + lane) * 32);
            short8 bre = *reinterpret_cast<const short8*>(t3);
            short8 bim = *reinterpret_cast<const short8*>(t3 + 16);
            sP = MFMA(are, bre, sP); sQ = MFMA(aim, bim, sQ);
            sI = MFMA(are, bim, sI); sI = MFMA(aim, bre, sI);
        }
        #pragma unroll
        for (int r = 0; r < 4; ++r) {
            int u = (lane >> 4) * 4 + r + 16 * mt;
            int c = (lane & 15) + 16 * nt;
            *(ushort_t*)(sm + ST_RE + c * 80 + u * 2) = f2bf(sP[r] - sQ[r]);
            *(ushort_t*)(sm + ST_IM + c * 80 + u * 2) = f2bf(sI[r]);
        }
    }
    __syncthreads();

    // ---- conv + spec MFMAs; stream results into padded LDS out buffer ----
    #pragma unroll
    for (int nt = 0; nt < 4; ++nt) {
        f32x4 acc = {0.f,0.f,0.f,0.f};
        #pragma unroll
        for (int ks = 0; ks < 2; ++ks) {
            short8 ah = *reinterpret_cast<const short8*>(
                sm + XB + ((lane & 15) + 16 * wv) * 144 + (lane >> 4) * 16 + 64 * ks);
            short8 bw = *reinterpret_cast<const short8*>(
                sm + CWT + ((lane & 15) + 16 * nt) * 144 + (lane >> 4) * 16 + 64 * ks);
            acc = MFMA(ah, bw, acc);
        }
        short8 bre = *reinterpret_cast<const short8*>(
            sm + ST_RE + ((lane & 15) + 16 * nt) * 80 + (lane >> 4) * 16);
        short8 bim = *reinterpret_cast<const short8*>(
            sm + ST_IM + ((lane & 15) + 16 * nt) * 80 + (lane >> 4) * 16);
        f32x4 sp = {0.f,0.f,0.f,0.f}, sq = {0.f,0.f,0.f,0.f};
        sp = MFMA(gre, bre, sp);
        sq = MFMA(gim, bim, sq);
        #pragma unroll
        for (int r = 0; r < 4; ++r) {
            int w = (lane >> 4) * 4 + r + 16 * wv;
            int c = (lane & 15) + 16 * nt;
            float v = acc[r] + ((const float*)(sm + SCB))[c] + sp[r] - sq[r];
            *(float*)(sm + OUTB + w * 272 + c * 4) = fmaxf(v, 0.0f);
        }
    }
    __syncthreads();

    // ---- fully coalesced nontemporal stores ----
    float* orow = out + ((size_t)(b * NHt + h)) * (NWd * NC);
    #pragma unroll
    for (int i = 0; i < 4; ++i) {
        int flat = tid + 512 * i;              // 0..2047 float4s
        int w = flat >> 4, c4 = (flat & 15) * 4;
        f32x4 v = *reinterpret_cast<const f32x4*>(sm + OUTB + w * 272 + c4 * 4);
        __builtin_nontemporal_store(v, reinterpret_cast<f32x4*>(orow + w * 64 + c4));
    }
}

// ---------------------------------------------------------------------------
// K3b (h>=32): pure 1x1 conv + bias + relu. No x staging in LDS — MFMA
// A-fragments of x loaded directly from global (lane = row (lane&15),
// k-offset (lane>>4)*8). 44 KB LDS -> 3 blocks/CU, one barrier pair.
// ---------------------------------------------------------------------------
__global__ __launch_bounds__(512, 6) void k3_conv(
    const float* __restrict__ x, const float* __restrict__ cw, const float* __restrict__ cb,
    float* __restrict__ out)
{
    const int b = blockIdx.x, h = blockIdx.y + MX;   // 32..127
    const int tid = threadIdx.x, lane = tid & 63, wv = tid >> 6;
    constexpr int CWT  = 0;      // conv_w^T [o64][i64+pad], stride 144B
    constexpr int SCB  = 9216;   // bias f32[64]
    constexpr int OUTB = 9472;   // out f32 [w128][c64+4pad], stride 272B
    __shared__ __align__(16) char sm[44288];

    // direct per-lane A-fragment loads of x (rows 16*wv+(lane&15))
    const float* xs = x + ((size_t)(b * NHt + h)) * (NWd * NC);
    const float* xrow = xs + (16 * wv + (lane & 15)) * 64 + (lane >> 4) * 8;
    f32x4 xa[4];
    #pragma unroll
    for (int ks = 0; ks < 2; ++ks) {
        xa[2*ks]   = __builtin_nontemporal_load(reinterpret_cast<const f32x4*>(xrow + 32 * ks));
        xa[2*ks+1] = __builtin_nontemporal_load(reinterpret_cast<const f32x4*>(xrow + 32 * ks + 4));
    }
    // stage conv_w^T + bias
    #pragma unroll
    for (int i = 0; i < 2; ++i) {
        int ii = (tid >> 4) + 32 * i;
        #pragma unroll
        for (int j = 0; j < 4; ++j) {
            int o = (tid & 15) + 16 * j;
            *(ushort_t*)(sm + CWT + o * 144 + ii * 2) = f2bf(cw[ii * 64 + o]);
        }
    }
    if (tid < 64) ((float*)(sm + SCB))[tid] = cb[tid];

    short8 afr[2];
    #pragma unroll
    for (int ks = 0; ks < 2; ++ks) {
        short8 t;
        #pragma unroll
        for (int j = 0; j < 4; ++j) {
            t[j]     = (short)f2bf(xa[2*ks][j]);
            t[4 + j] = (short)f2bf(xa[2*ks+1][j]);
        }
        afr[ks] = t;
    }
    __syncthreads();

    #pragma unroll
    for (int nt = 0; nt < 4; ++nt) {
        f32x4 acc = {0.f,0.f,0.f,0.f};
        #pragma unroll
        for (int ks = 0; ks < 2; ++ks) {
            short8 bw = *reinterpret_cast<const short8*>(
                sm + CWT + ((lane & 15) + 16 * nt) * 144 + (lane >> 4) * 16 + 64 * ks);
            acc = MFMA(afr[ks], bw, acc);
        }
        #pragma unroll
        for (int r = 0; r < 4; ++r) {
            int w = (lane >> 4) * 4 + r + 16 * wv;
            int c = (lane & 15) + 16 * nt;
            float v = acc[r] + ((const float*)(sm + SCB))[c];
            *(float*)(sm + OUTB + w * 272 + c * 4) = fmaxf(v, 0.0f);
        }
    }
    __syncthreads();

    float* orow = out + ((size_t)(b * NHt + h)) * (NWd * NC);
    #pragma unroll
    for (int i = 0; i < 4; ++i) {
        int flat = tid + 512 * i;              // 0..2047 float4s
        int w = flat >> 4, c4 = (flat & 15) * 4;
        f32x4 v = *reinterpret_cast<const f32x4*>(sm + OUTB + w * 272 + c4 * 4);
        __builtin_nontemporal_store(v, reinterpret_cast<f32x4*>(orow + w * 64 + c4));
    }
}

extern "C" void kernel_launch(void* const* d_in, const int* in_sizes, int n_in,
                              void* d_out, int out_size, void* d_ws, size_t ws_size,
                              hipStream_t stream) {
    const float* x      = (const float*)d_in[0];
    const float* w_real = (const float*)d_in[1];
    const float* w_imag = (const float*)d_in[2];
    const float* conv_w = (const float*)d_in[3];
    const float* conv_b = (const float*)d_in[4];
    float* out = (float*)d_out;

    ushort_t* tabs = (ushort_t*)d_ws;
    ushort_t* XY   = (ushort_t*)((char*)d_ws + XY_OFF);

    k0_tables<<<8, 256, 0, stream>>>(tabs);
    k1_fwd<<<dim3(NB, MX), 512, 0, stream>>>(x, (const char*)d_ws, XY);
    k2_mix<<<dim3(MX, 32), 256, 0, stream>>>(w_real, w_imag, XY);
    k3_conv<<<dim3(NB, NHt - MX), 512, 0, stream>>>(x, conv_w, conv_b, out);
    k3_spec<<<dim3(NB, MX), 512, 0, stream>>>(x, conv_w, conv_b,
                                              (const char*)d_ws, XY, out);
}

// Round 6
// 84.476 us; speedup vs baseline: 1.0327x; 1.0327x over previous
//
#include <hip/hip_runtime.h>

typedef __attribute__((ext_vector_type(8))) short short8;
typedef __attribute__((ext_vector_type(4))) short bf16x4;
typedef __attribute__((ext_vector_type(4))) float f32x4;
typedef unsigned short ushort_t;

#define MFMA(a, b, c) __builtin_amdgcn_mfma_f32_16x16x32_bf16((a), (b), (c), 0, 0, 0)

constexpr int NB = 32, NHt = 128, NWd = 128, NC = 64, MX = 32;
constexpr float TWO_PI = 6.28318530717958647692f;

// workspace layout (64 KB tables + 8 MiB X/Y buffer)
constexpr size_t TAB_T3 = 32768;  // K3 stage4 B: G64  inv  [nt4][ks2][lane64][re8,im8]
constexpr size_t TAB_T4 = 49152;  // K3 stage5 A: G128 inv  [mt8][lane64][re8,im8] (x 1/8192)
constexpr size_t XY_OFF = 65536;  // X then Y in-place: bf16 [h32][u32][comp2][b32][k64]

__device__ inline ushort_t f2bf(float f) {
    union { float f; unsigned int u; } v; v.f = f;
    unsigned int r = v.u + 0x7FFFu + ((v.u >> 16) & 1u);   // RTN-even
    return (ushort_t)(r >> 16);
}
// row-dependent XOR swizzle (bits 4-5): breaks the {0,16} bank pattern of
// power-of-two-ish row strides; 16B-granular so ds_read_b128 stays aligned.
__device__ inline int sxor(int row) { return ((row >> 3) & 3) << 4; }

// ---------------------------------------------------------------------------
// K1: per (b, h<32). M1 = F128trunc . x  (32x64 cplx), X = M1 . G64fwd.
// T1/T2 twiddle fragments computed INLINE (no k0 kernel); the lead block
// (b==0,h==0) additionally writes K3's T3/T4 tables to the workspace —
// k3 launches after k1, so the kernel boundary orders the write.
// ---------------------------------------------------------------------------
__global__ __launch_bounds__(512) void k1_fwd(
    const float* __restrict__ x, char* __restrict__ tabs, ushort_t* __restrict__ XY)
{
    const int b = blockIdx.x, h = blockIdx.y;
    const int tid = threadIdx.x, lane = tid & 63, wv = tid >> 6;
    constexpr int SXT  = 0;            // x^T bf16 [c64][w128], stride 272B; reused for X-out
    constexpr int M1RE = 17408;        // [u32][c64+pad], stride 144B
    constexpr int M1IM = 17408 + 4608;
    __shared__ __align__(16) char sm[26624];

    // ---- lead block: emit T3/T4 tables for k3 (512 entries each) ----
    if (b == 0 && h == 0) {
        {   // T3: G64 inv  exp(+2pi i o c/64); entry = tid
            int nt2 = tid >> 7, ks2 = (tid >> 6) & 1, l = tid & 63;
            int cc2 = (l & 15) + 16 * nt2, ob = (l >> 4) * 8 + 32 * ks2;
            short8 vre, vim;
            #pragma unroll
            for (int j = 0; j < 8; ++j) {
                float a = (float)(((ob + j) * cc2) & 63) * (TWO_PI / 64.f);
                float s, c; __sincosf(a, &s, &c);
                vre[j] = (short)f2bf(c); vim[j] = (short)f2bf(s);
            }
            *reinterpret_cast<short8*>(tabs + TAB_T3 + tid * 32)      = vre;
            *reinterpret_cast<short8*>(tabs + TAB_T3 + tid * 32 + 16) = vim;
        }
        {   // T4: G128 inv exp(+2pi i w u/128) * 2^-13; entry = tid
            int mt2 = tid >> 6, l = tid & 63;
            int w = (l & 15) + 16 * mt2, ub = (l >> 4) * 8;
            short8 vre, vim;
            #pragma unroll
            for (int j = 0; j < 8; ++j) {
                float a = (float)((w * (ub + j)) & 127) * (TWO_PI / 128.f);
                float s, c; __sincosf(a, &s, &c);
                vre[j] = (short)f2bf(c * 0.0001220703125f);  // exact 2^-13
                vim[j] = (short)f2bf(s * 0.0001220703125f);
            }
            *reinterpret_cast<short8*>(tabs + TAB_T4 + tid * 32)      = vre;
            *reinterpret_cast<short8*>(tabs + TAB_T4 + tid * 32 + 16) = vim;
        }
    }

    // ---- load x slice (float4) + transpose -> sxT[c][w] bf16 (swizzled) ----
    const float* xs = x + ((size_t)(b * NHt + h)) * (NWd * NC);
    #pragma unroll
    for (int i = 0; i < 4; ++i) {
        int idx = tid + 512 * i;               // 0..2047 float4s
        int w = idx >> 4, c4 = (idx & 15) * 4;
        f32x4 v = *reinterpret_cast<const f32x4*>(xs + w * 64 + c4);
        #pragma unroll
        for (int j = 0; j < 4; ++j)
            *(ushort_t*)(sm + SXT + (c4 + j) * 272 + ((w * 2) ^ sxor(c4 + j))) = f2bf(v[j]);
    }
    __syncthreads();

    const int mt = wv >> 2, nt = wv & 3;
    // stage 1: M1[u,c] = sum_w F[u,w] x[w,c]; F-frag computed inline
    f32x4 m1r = {0.f,0.f,0.f,0.f}, m1i = {0.f,0.f,0.f,0.f};
    const int cc = (lane & 15) + 16 * nt;
    const int uu = (lane & 15) + 16 * mt;
    #pragma unroll
    for (int ks = 0; ks < 4; ++ks) {
        short8 bfrag = *reinterpret_cast<const short8*>(
            sm + SXT + cc * 272 + (((lane >> 4) * 16 + 64 * ks) ^ sxor(cc)));
        int wb = (lane >> 4) * 8 + 32 * ks;
        short8 are, aim;
        #pragma unroll
        for (int j = 0; j < 8; ++j) {
            float a = (float)((uu * (wb + j)) & 127) * (TWO_PI / 128.f);
            float s, c; __sincosf(a, &s, &c);
            are[j] = (short)f2bf(c); aim[j] = (short)f2bf(-s);
        }
        m1r = MFMA(are, bfrag, m1r);
        m1i = MFMA(aim, bfrag, m1i);
    }
    #pragma unroll
    for (int r = 0; r < 4; ++r) {
        int u = (lane >> 4) * 4 + r + 16 * mt;
        int c = (lane & 15) + 16 * nt;
        *(ushort_t*)(sm + M1RE + u * 144 + c * 2) = f2bf(m1r[r]);
        *(ushort_t*)(sm + M1IM + u * 144 + c * 2) = f2bf(m1i[r]);
    }
    __syncthreads();

    // stage 2: X[u,k] = sum_c M1[u,c] G64f[c,k]; G-frag inline; out via LDS
    f32x4 xP = {0.f,0.f,0.f,0.f}, xQ = {0.f,0.f,0.f,0.f}, xI = {0.f,0.f,0.f,0.f};
    const int kk = (lane & 15) + 16 * nt;
    #pragma unroll
    for (int ks = 0; ks < 2; ++ks) {
        short8 are = *reinterpret_cast<const short8*>(
            sm + M1RE + ((lane & 15) + 16 * mt) * 144 + (lane >> 4) * 16 + 64 * ks);
        short8 aim = *reinterpret_cast<const short8*>(
            sm + M1IM + ((lane & 15) + 16 * mt) * 144 + (lane >> 4) * 16 + 64 * ks);
        int cb2 = (lane >> 4) * 8 + 32 * ks;
        short8 bre, bim;
        #pragma unroll
        for (int j = 0; j < 8; ++j) {
            float a = (float)((kk * (cb2 + j)) & 63) * (TWO_PI / 64.f);
            float s, c; __sincosf(a, &s, &c);
            bre[j] = (short)f2bf(c); bim[j] = (short)f2bf(-s);
        }
        xP = MFMA(are, bre, xP);
        xQ = MFMA(aim, bim, xQ);
        xI = MFMA(are, bim, xI);
        xI = MFMA(aim, bre, xI);
    }
    #pragma unroll
    for (int r = 0; r < 4; ++r) {
        int u = (lane >> 4) * 4 + r + 16 * mt;
        int k = (lane & 15) + 16 * nt;
        *(ushort_t*)(sm + SXT + 0    + u * 128 + k * 2) = f2bf(xP[r] - xQ[r]);
        *(ushort_t*)(sm + SXT + 4096 + u * 128 + k * 2) = f2bf(xI[r]);
    }
    __syncthreads();

    // coalesced X store: thread -> (u, comp, k8)
    {
        int u = tid >> 4, comp = (tid >> 3) & 1, k8 = (tid & 7) * 8;
        short8 v = *reinterpret_cast<const short8*>(sm + SXT + comp * 4096 + u * 128 + k8 * 2);
        size_t hu = (size_t)(h * 32 + u);
        *reinterpret_cast<short8*>(XY + ((hu * 2 + comp) * 32 + b) * 64 + k8) = v;
    }
}

// ---------------------------------------------------------------------------
// K2: per (h, u). Y[b,o] = sum_k X[b,k] W[h,u,k,o] — b-batched so W is read
// from HBM exactly once.
// ---------------------------------------------------------------------------
__global__ __launch_bounds__(256) void k2_mix(
    const float* __restrict__ wre, const float* __restrict__ wim, ushort_t* __restrict__ XY)
{
    const int h = blockIdx.x, u = blockIdx.y;
    const int tid = threadIdx.x, lane = tid & 63, wv = tid >> 6;   // 4 waves
    constexpr int XRE = 0, XIM = 4608, WTR = 9216, WTI = 18432;    // strides 144B
    __shared__ __align__(16) char sm[27648];
    const size_t hu = (size_t)(h * 32 + u);

    #pragma unroll
    for (int it = 0; it < 2; ++it) {        // stage X[b][k] (both comps)
        int row = (tid >> 3) + 32 * it;
        int comp = row >> 5, bb = row & 31, k8 = (tid & 7) * 8;
        short8 v = *reinterpret_cast<const short8*>(XY + ((hu * 2 + comp) * 32 + bb) * 64 + k8);
        *reinterpret_cast<short8*>(sm + (comp ? XIM : XRE) + bb * 144 + k8 * 2) = v;
    }
    const float* wr = wre + hu * 4096;      // transpose W -> WT[o][k] bf16 (swizzled)
    const float* wi = wim + hu * 4096;
    #pragma unroll
    for (int i = 0; i < 4; ++i) {
        int idx = tid + 256 * i;            // 0..1023
        int k = idx >> 4, o4 = (idx & 15) * 4;
        f32x4 vr = __builtin_nontemporal_load(reinterpret_cast<const f32x4*>(wr + k * 64 + o4));
        f32x4 vi = __builtin_nontemporal_load(reinterpret_cast<const f32x4*>(wi + k * 64 + o4));
        #pragma unroll
        for (int j = 0; j < 4; ++j) {
            int o = o4 + j, koff = (k * 2) ^ sxor(o);
            *(ushort_t*)(sm + WTR + o * 144 + koff) = f2bf(vr[j]);
            *(ushort_t*)(sm + WTI + o * 144 + koff) = f2bf(vi[j]);
        }
    }
    __syncthreads();

    const int mt = wv >> 1;
    f32x4 yRe[2], yIm[2];
    #pragma unroll
    for (int half = 0; half < 2; ++half) {
        const int nt = (wv & 1) * 2 + half;
        const int oo = (lane & 15) + 16 * nt;
        f32x4 yP = {0.f,0.f,0.f,0.f}, yQ = {0.f,0.f,0.f,0.f}, yI = {0.f,0.f,0.f,0.f};
        #pragma unroll
        for (int ks = 0; ks < 2; ++ks) {
            int woff = ((lane >> 4) * 16 + 64 * ks) ^ sxor(oo);
            short8 are = *reinterpret_cast<const short8*>(
                sm + XRE + ((lane & 15) + 16 * mt) * 144 + (lane >> 4) * 16 + 64 * ks);
            short8 aim = *reinterpret_cast<const short8*>(
                sm + XIM + ((lane & 15) + 16 * mt) * 144 + (lane >> 4) * 16 + 64 * ks);
            short8 bre = *reinterpret_cast<const short8*>(sm + WTR + oo * 144 + woff);
            short8 bim = *reinterpret_cast<const short8*>(sm + WTI + oo * 144 + woff);
            yP = MFMA(are, bre, yP); yQ = MFMA(aim, bim, yQ);
            yI = MFMA(are, bim, yI); yI = MFMA(aim, bre, yI);
        }
        #pragma unroll
        for (int r = 0; r < 4; ++r) { yRe[half][r] = yP[r] - yQ[r]; yIm[half][r] = yI[r]; }
    }
    __syncthreads();   // X region dead; reuse as Y-out [comp][b][o] bf16

    #pragma unroll
    for (int half = 0; half < 2; ++half) {
        const int nt = (wv & 1) * 2 + half;
        #pragma unroll
        for (int r = 0; r < 4; ++r) {
            int bb = (lane >> 4) * 4 + r + 16 * mt;
            int o = (lane & 15) + 16 * nt;
            *(ushort_t*)(sm + 0    + bb * 128 + o * 2) = f2bf(yRe[half][r]);
            *(ushort_t*)(sm + 4096 + bb * 128 + o * 2) = f2bf(yIm[half][r]);
        }
    }
    __syncthreads();

    #pragma unroll
    for (int it = 0; it < 2; ++it) {        // coalesced Y store: 8 KB contiguous
        int flat = tid + 256 * it;          // (comp,b,o8) in global order
        short8 v = *reinterpret_cast<const short8*>(sm + flat * 16);
        *reinterpret_cast<short8*>(XY + hu * 4096 + flat * 8) = v;
    }
}

// ---------------------------------------------------------------------------
// K3: per (b, h). h<32: S = Y.G64inv, spec = Re(G128inv.S) (1/8192 in table).
// All h: conv (x bf16) + bias + relu. Output staged in padded LDS buffer ->
// fully coalesced nontemporal dwordx4 stores.
// ---------------------------------------------------------------------------
__global__ __launch_bounds__(512, 4) void k3_inv(
    const float* __restrict__ x, const float* __restrict__ cw, const float* __restrict__ cb,
    const char* __restrict__ tabs, const ushort_t* __restrict__ XY, float* __restrict__ out)
{
    const int b = blockIdx.x, h = blockIdx.y;
    const int tid = threadIdx.x, lane = tid & 63, wv = tid >> 6;
    constexpr int ST_RE = 0, ST_IM = 5120;   // S^T [c64][u32+pad], stride 80B
    constexpr int XB   = 10240;              // x bf16 [w128][c64+pad], stride 144B
    constexpr int CWT  = 28672;              // conv_w^T [o64][i64+pad], stride 144B
    constexpr int SCB  = 37888;              // bias f32[64]
    constexpr int OUTB = 38144;              // out f32 [w128][c64+4pad], stride 272B
    constexpr int YRE  = 38144;              // Y staging inside OUTB (dead by store time)
    constexpr int YIM  = 38144 + 4608;       // strides 144B
    __shared__ __align__(16) char sm[72960];

    // ---- issue all global loads up front ----
    const float* xs = x + ((size_t)(b * NHt + h)) * (NWd * NC);
    f32x4 xv[4];
    #pragma unroll
    for (int i = 0; i < 4; ++i) {
        int idx = tid + 512 * i;
        int w = idx >> 4, c4 = (idx & 15) * 4;
        xv[i] = __builtin_nontemporal_load(reinterpret_cast<const f32x4*>(xs + w * 64 + c4));
    }
    short8 yv = {}, gre = {}, gim = {};
    if (h < MX) {
        int u = tid >> 4, comp = (tid >> 3) & 1, o8 = (tid & 7) * 8;
        size_t hu = (size_t)(h * 32 + u);
        yv = *reinterpret_cast<const short8*>(XY + ((hu * 2 + comp) * 32 + b) * 64 + o8);
        const char* t4 = tabs + TAB_T4 + ((wv * 64 + lane) * 32);
        gre = *reinterpret_cast<const short8*>(t4);
        gim = *reinterpret_cast<const short8*>(t4 + 16);
    }

    // ---- stage x (bf16, packed 8B writes), conv_w^T, bias ----
    #pragma unroll
    for (int i = 0; i < 4; ++i) {
        int idx = tid + 512 * i;
        int w = idx >> 4, c4 = (idx & 15) * 4;
        bf16x4 pk = { (short)f2bf(xv[i][0]), (short)f2bf(xv[i][1]),
                      (short)f2bf(xv[i][2]), (short)f2bf(xv[i][3]) };
        *reinterpret_cast<bf16x4*>(sm + XB + w * 144 + c4 * 2) = pk;
    }
    #pragma unroll
    for (int i = 0; i < 2; ++i) {
        int ii = (tid >> 4) + 32 * i;
        #pragma unroll
        for (int j = 0; j < 4; ++j) {
            int o = (tid & 15) + 16 * j;
            *(ushort_t*)(sm + CWT + o * 144 + ii * 2) = f2bf(cw[ii * 64 + o]);
        }
    }
    if (tid < 64) ((float*)(sm + SCB))[tid] = cb[tid];

    if (h < MX) {
        {   // Y -> LDS (its own region; does not alias XB)
            int u = tid >> 4, comp = (tid >> 3) & 1, o8 = (tid & 7) * 8;
            *reinterpret_cast<short8*>(sm + (comp ? YIM : YRE) + u * 144 + o8 * 2) = yv;
        }
        __syncthreads();
        // stage 4: S[u,c] = sum_o Y[u,o] G64inv[o,c]; write S transposed [c][u]
        const int mt = wv >> 2, nt = wv & 3;
        f32x4 sP = {0.f,0.f,0.f,0.f}, sQ = {0.f,0.f,0.f,0.f}, sI = {0.f,0.f,0.f,0.f};
        #pragma unroll
        for (int ks = 0; ks < 2; ++ks) {
            short8 are = *reinterpret_cast<const short8*>(
                sm + YRE + ((lane & 15) + 16 * mt) * 144 + (lane >> 4) * 16 + 64 * ks);
            short8 aim = *reinterpret_cast<const short8*>(
                sm + YIM + ((lane & 15) + 16 * mt) * 144 + (lane >> 4) * 16 + 64 * ks);
            const char* t3 = tabs + TAB_T3 + (((nt * 2 + ks) * 64 + lane) * 32);
            short8 bre = *reinterpret_cast<const short8*>(t3);
            short8 bim = *reinterpret_cast<const short8*>(t3 + 16);
            sP = MFMA(are, bre, sP); sQ = MFMA(aim, bim, sQ);
            sI = MFMA(are, bim, sI); sI = MFMA(aim, bre, sI);
        }
        #pragma unroll
        for (int r = 0; r < 4; ++r) {
            int u = (lane >> 4) * 4 + r + 16 * mt;
            int c = (lane & 15) + 16 * nt;
            *(ushort_t*)(sm + ST_RE + c * 80 + u * 2) = f2bf(sP[r] - sQ[r]);
            *(ushort_t*)(sm + ST_IM + c * 80 + u * 2) = f2bf(sI[r]);
        }
    }
    __syncthreads();

    // ---- conv + spec MFMAs; stream results into padded LDS out buffer ----
    #pragma unroll
    for (int nt = 0; nt < 4; ++nt) {
        f32x4 acc = {0.f,0.f,0.f,0.f};
        #pragma unroll
        for (int ks = 0; ks < 2; ++ks) {
            short8 ah = *reinterpret_cast<const short8*>(
                sm + XB + ((lane & 15) + 16 * wv) * 144 + (lane >> 4) * 16 + 64 * ks);
            short8 bw = *reinterpret_cast<const short8*>(
                sm + CWT + ((lane & 15) + 16 * nt) * 144 + (lane >> 4) * 16 + 64 * ks);
            acc = MFMA(ah, bw, acc);
        }
        f32x4 sp = {0.f,0.f,0.f,0.f}, sq = {0.f,0.f,0.f,0.f};
        if (h < MX) {
            short8 bre = *reinterpret_cast<const short8*>(
                sm + ST_RE + ((lane & 15) + 16 * nt) * 80 + (lane >> 4) * 16);
            short8 bim = *reinterpret_cast<const short8*>(
                sm + ST_IM + ((lane & 15) + 16 * nt) * 80 + (lane >> 4) * 16);
            sp = MFMA(gre, bre, sp);
            sq = MFMA(gim, bim, sq);
        }
        #pragma unroll
        for (int r = 0; r < 4; ++r) {
            int w = (lane >> 4) * 4 + r + 16 * wv;
            int c = (lane & 15) + 16 * nt;
            float v = acc[r] + ((const float*)(sm + SCB))[c];
            if (h < MX) v += sp[r] - sq[r];            // 1/8192 folded into T4
            *(float*)(sm + OUTB + w * 272 + c * 4) = fmaxf(v, 0.0f);
        }
    }
    __syncthreads();

    // ---- fully coalesced nontemporal stores ----
    float* orow = out + ((size_t)(b * NHt + h)) * (NWd * NC);
    #pragma unroll
    for (int i = 0; i < 4; ++i) {
        int flat = tid + 512 * i;              // 0..2047 float4s
        int w = flat >> 4, c4 = (flat & 15) * 4;
        f32x4 v = *reinterpret_cast<const f32x4*>(sm + OUTB + w * 272 + c4 * 4);
        __builtin_nontemporal_store(v, reinterpret_cast<f32x4*>(orow + w * 64 + c4));
    }
}

extern "C" void kernel_launch(void* const* d_in, const int* in_sizes, int n_in,
                              void* d_out, int out_size, void* d_ws, size_t ws_size,
                              hipStream_t stream) {
    const float* x      = (const float*)d_in[0];
    const float* w_real = (const float*)d_in[1];
    const float* w_imag = (const float*)d_in[2];
    const float* conv_w = (const float*)d_in[3];
    const float* conv_b = (const float*)d_in[4];
    float* out = (float*)d_out;

    char* tabs   = (char*)d_ws;
    ushort_t* XY = (ushort_t*)((char*)d_ws + XY_OFF);

    k1_fwd<<<dim3(NB, MX), 512, 0, stream>>>(x, tabs, XY);
    k2_mix<<<dim3(MX, 32), 256, 0, stream>>>(w_real, w_imag, XY);
    k3_inv<<<dim3(NB, NHt), 512, 0, stream>>>(x, conv_w, conv_b,
                                              (const char*)tabs, XY, out);
}